// Round 6
// baseline (852.924 us; speedup 1.0000x reference)
//
#include <hip/hip_runtime.h>
#include <math.h>

#define BH 32
#define N_ 4096
#define D_ 64
#define M_ 256
#define L_ 16
#define DIM_ 512
#define K3_ 1536

typedef __attribute__((ext_vector_type(4))) float f32x4;
typedef __attribute__((ext_vector_type(8))) short s16x8;
typedef unsigned short ushort_t;

__device__ inline ushort_t f2bf(float f){
  union{float f; unsigned u;} v; v.f = f;
  unsigned r = v.u + 0x7fffu + ((v.u >> 16) & 1u);
  return (ushort_t)(r >> 16);
}
__device__ inline float bf2f(ushort_t b){
  union{unsigned u; float f;} v; v.u = ((unsigned)b) << 16; return v.f;
}

// ---------- reduction helpers ----------
__device__ inline float wave_sum(float v){
  #pragma unroll
  for (int o=32;o;o>>=1) v += __shfl_down(v,o,64);
  return v;
}
__device__ inline float wave_max(float v){
  #pragma unroll
  for (int o=32;o;o>>=1) v = fmaxf(v,__shfl_down(v,o,64));
  return v;
}
__device__ inline float blk_sum256(float v, float* sm){
  v = wave_sum(v);
  int lane = threadIdx.x & 63, wid = threadIdx.x >> 6;
  if (lane==0) sm[wid]=v;
  __syncthreads();
  float r = sm[0]+sm[1]+sm[2]+sm[3];
  __syncthreads();
  return r;
}
__device__ inline float blk_max256(float v, float* sm){
  v = wave_max(v);
  int lane = threadIdx.x & 63, wid = threadIdx.x >> 6;
  if (lane==0) sm[wid]=v;
  __syncthreads();
  float r = fmaxf(fmaxf(sm[0],sm[1]),fmaxf(sm[2],sm[3]));
  __syncthreads();
  return r;
}

// ---------- 1. LayerNorm -> bf16 ----------
__global__ __launch_bounds__(256) void ln_k(const float* __restrict__ x,
    const float* __restrict__ g, const float* __restrict__ bt, ushort_t* __restrict__ xn){
  int row = blockIdx.x, t = threadIdx.x;
  __shared__ float sm[4];
  const float* xr = x + (size_t)row*DIM_;
  float v0 = xr[t], v1 = xr[t+256];
  float mu = blk_sum256(v0+v1, sm) * (1.f/DIM_);
  float d0 = v0-mu, d1 = v1-mu;
  float var = blk_sum256(d0*d0+d1*d1, sm) * (1.f/DIM_);
  float rs = rsqrtf(var + 1e-5f);
  ushort_t* xo = xn + (size_t)row*DIM_;
  xo[t]     = f2bf(d0*rs*g[t]     + bt[t]);
  xo[t+256] = f2bf(d1*rs*g[t+256] + bt[t+256]);
}

// ---------- transpose fp32 [R][C] -> bf16 [C][R], batched via z ----------
__global__ __launch_bounds__(256) void twb_k(const float* __restrict__ src,
    ushort_t* __restrict__ dst, int R, int C){
  __shared__ ushort_t tile[64][66];
  size_t boff = (size_t)blockIdx.z * R * C;
  int r0 = blockIdx.y*64, c0 = blockIdx.x*64;
  int t = threadIdx.x, c = t & 63, r4 = t >> 6;
  #pragma unroll
  for (int i=0;i<16;i++){
    int rr = r4 + i*4;
    tile[c][rr] = f2bf(src[boff + (size_t)(r0+rr)*C + (c0+c)]);
  }
  __syncthreads();
  #pragma unroll
  for (int i=0;i<16;i++){
    int cc = r4 + i*4;
    dst[boff + (size_t)(c0+cc)*R + (r0 + c)] = tile[cc][c];
  }
}
// ---------- transpose bf16 [R][C] -> bf16 [C][R], batched ----------
__global__ __launch_bounds__(256) void tbb_k(const ushort_t* __restrict__ src,
    ushort_t* __restrict__ dst, int R, int C){
  __shared__ ushort_t tile[64][66];
  size_t boff = (size_t)blockIdx.z * R * C;
  int r0 = blockIdx.y*64, c0 = blockIdx.x*64;
  int t = threadIdx.x, c = t & 63, r4 = t >> 6;
  #pragma unroll
  for (int i=0;i<16;i++){
    int rr = r4 + i*4;
    tile[c][rr] = src[boff + (size_t)(r0+rr)*C + (c0+c)];
  }
  __syncthreads();
  #pragma unroll
  for (int i=0;i<16;i++){
    int cc = r4 + i*4;
    dst[boff + (size_t)(c0+cc)*R + (r0 + c)] = tile[cc][c];
  }
}

// ---------- 2. QKV GEMM bf16 MFMA ----------
__global__ __launch_bounds__(256) void gemm_qkv_k(const ushort_t* __restrict__ A,
    const ushort_t* __restrict__ Bt, ushort_t* __restrict__ qb, ushort_t* __restrict__ kb,
    ushort_t* __restrict__ vb){
  __shared__ __align__(16) ushort_t As[128*72];
  __shared__ __align__(16) ushort_t Bs[128*72];
  int t = threadIdx.x;
  int lane = t & 63, wave = t >> 6;
  int l16 = lane & 15, quad = lane >> 4;
  int wm = (wave & 1) * 64, wn = (wave >> 1) * 64;
  int row0 = blockIdx.y * 128, col0 = blockIdx.x * 128;
  f32x4 acc[4][4];
  #pragma unroll
  for (int i=0;i<4;i++)
    #pragma unroll
    for (int j=0;j<4;j++) acc[i][j] = (f32x4){0.f,0.f,0.f,0.f};
  int sr = t >> 3, sc = (t & 7) * 8;
  for (int k0=0;k0<DIM_;k0+=64){
    __syncthreads();
    #pragma unroll
    for (int p=0;p<4;p++){
      int r = sr + p*32;
      *(uint4*)&As[r*72 + sc] = *(const uint4*)&A[(size_t)(row0+r)*DIM_ + k0 + sc];
      *(uint4*)&Bs[r*72 + sc] = *(const uint4*)&Bt[(size_t)(col0+r)*DIM_ + k0 + sc];
    }
    __syncthreads();
    s16x8 af[4][2], bf[4][2];
    #pragma unroll
    for (int mt=0;mt<4;mt++)
      #pragma unroll
      for (int kk=0;kk<2;kk++)
        af[mt][kk] = *(const s16x8*)&As[(wm + mt*16 + l16)*72 + kk*32 + quad*8];
    #pragma unroll
    for (int nt=0;nt<4;nt++)
      #pragma unroll
      for (int kk=0;kk<2;kk++)
        bf[nt][kk] = *(const s16x8*)&Bs[(wn + nt*16 + l16)*72 + kk*32 + quad*8];
    #pragma unroll
    for (int mt=0;mt<4;mt++)
      #pragma unroll
      for (int nt=0;nt<4;nt++)
        #pragma unroll
        for (int kk=0;kk<2;kk++)
          acc[mt][nt] = __builtin_amdgcn_mfma_f32_16x16x32_bf16(af[mt][kk], bf[nt][kk], acc[mt][nt], 0,0,0);
  }
  #pragma unroll
  for (int mt=0;mt<4;mt++){
    #pragma unroll
    for (int nt=0;nt<4;nt++){
      #pragma unroll
      for (int reg=0;reg<4;reg++){
        int row = row0 + wm + mt*16 + quad*4 + reg;
        int col = col0 + wn + nt*16 + l16;
        float val = acc[mt][nt][reg];
        int b = row >> 12, n = row & 4095;
        int which = col >> 9, rem = col & 511;
        int h = rem >> 6, d = rem & 63;
        size_t dst = ((size_t)((b<<3)+h)*N_ + n)*D_ + d;
        if (which==0)      qb[dst] = f2bf(val*0.125f);
        else if (which==1) kb[dst] = f2bf(val);
        else               vb[dst] = f2bf(val);
      }
    }
  }
}

// ---------- final GEMM bf16 MFMA ----------
__global__ __launch_bounds__(256) void final_k(const ushort_t* __restrict__ A,
    const ushort_t* __restrict__ Bt, const float* __restrict__ bo,
    const float* __restrict__ x, float* __restrict__ y){
  __shared__ __align__(16) ushort_t As[128*72];
  __shared__ __align__(16) ushort_t Bs[128*72];
  int t = threadIdx.x;
  int lane = t & 63, wave = t >> 6;
  int l16 = lane & 15, quad = lane >> 4;
  int wm = (wave & 1) * 64, wn = (wave >> 1) * 64;
  int row0 = blockIdx.y * 128, col0 = blockIdx.x * 128;
  f32x4 acc[4][4];
  #pragma unroll
  for (int i=0;i<4;i++)
    #pragma unroll
    for (int j=0;j<4;j++) acc[i][j] = (f32x4){0.f,0.f,0.f,0.f};
  int sr = t >> 3, sc = (t & 7) * 8;
  for (int k0=0;k0<DIM_;k0+=64){
    __syncthreads();
    #pragma unroll
    for (int p=0;p<4;p++){
      int r = sr + p*32;
      *(uint4*)&As[r*72 + sc] = *(const uint4*)&A[(size_t)(row0+r)*DIM_ + k0 + sc];
      *(uint4*)&Bs[r*72 + sc] = *(const uint4*)&Bt[(size_t)(col0+r)*DIM_ + k0 + sc];
    }
    __syncthreads();
    s16x8 af[4][2], bf[4][2];
    #pragma unroll
    for (int mt=0;mt<4;mt++)
      #pragma unroll
      for (int kk=0;kk<2;kk++)
        af[mt][kk] = *(const s16x8*)&As[(wm + mt*16 + l16)*72 + kk*32 + quad*8];
    #pragma unroll
    for (int nt=0;nt<4;nt++)
      #pragma unroll
      for (int kk=0;kk<2;kk++)
        bf[nt][kk] = *(const s16x8*)&Bs[(wn + nt*16 + l16)*72 + kk*32 + quad*8];
    #pragma unroll
    for (int mt=0;mt<4;mt++)
      #pragma unroll
      for (int nt=0;nt<4;nt++)
        #pragma unroll
        for (int kk=0;kk<2;kk++)
          acc[mt][nt] = __builtin_amdgcn_mfma_f32_16x16x32_bf16(af[mt][kk], bf[nt][kk], acc[mt][nt], 0,0,0);
  }
  #pragma unroll
  for (int mt=0;mt<4;mt++){
    #pragma unroll
    for (int nt=0;nt<4;nt++){
      #pragma unroll
      for (int reg=0;reg<4;reg++){
        int row = row0 + wm + mt*16 + quad*4 + reg;
        int col = col0 + wn + nt*16 + l16;
        size_t o = (size_t)row*DIM_ + col;
        y[o] = acc[mt][nt][reg] + bo[col] + x[o];
      }
    }
  }
}

// ---------- 3. landmark means (fp32 + bf16 h/l splits) ----------
__global__ void lmk_k(const ushort_t* __restrict__ q, const ushort_t* __restrict__ k,
                      float* __restrict__ ql, float* __restrict__ kl,
                      ushort_t* __restrict__ qlh, ushort_t* __restrict__ qll,
                      ushort_t* __restrict__ klh, ushort_t* __restrict__ kll){
  int idx = blockIdx.x*256 + threadIdx.x;
  int d = idx & 63, i = (idx >> 6) & 255, bh = idx >> 14;
  size_t base = ((size_t)bh*N_ + i*L_)*D_ + d;
  float sq=0.f, sk=0.f;
  #pragma unroll
  for (int tt=0;tt<L_;tt++){ sq += bf2f(q[base + (size_t)tt*D_]); sk += bf2f(k[base + (size_t)tt*D_]); }
  sq *= (1.f/L_); sk *= (1.f/L_);
  ql[idx] = sq; kl[idx] = sk;
  ushort_t qh = f2bf(sq), kh = f2bf(sk);
  qlh[idx] = qh; qll[idx] = f2bf(sq - bf2f(qh));
  klh[idx] = kh; kll[idx] = f2bf(sk - bf2f(kh));
}

// ---------- 4. attn2 via split-bf16 MFMA, fused row/col sums ----------
// grid (4, 32): blockIdx.x = 64-row group, blockIdx.y = bh. 4 waves x 16 rows.
__global__ __launch_bounds__(256) void attn2m_k(
    const ushort_t* __restrict__ qlh, const ushort_t* __restrict__ qll,
    const ushort_t* __restrict__ klh, const ushort_t* __restrict__ kll,
    float* __restrict__ a2f, ushort_t* __restrict__ a2h, ushort_t* __restrict__ a2l,
    float* __restrict__ cs, float* __restrict__ rs){
  int bh = blockIdx.y;
  int t = threadIdx.x, wave = t >> 6, lane = t & 63;
  int l16 = lane & 15, quad = lane >> 4;
  size_t mo = (size_t)bh*M_*M_;
  int rowtile = blockIdx.x*64 + wave*16;
  size_t qbase = ((size_t)bh*M_ + rowtile + l16)*D_;
  s16x8 qh0 = *(const s16x8*)&qlh[qbase + quad*8];
  s16x8 qh1 = *(const s16x8*)&qlh[qbase + 32 + quad*8];
  s16x8 qv0 = *(const s16x8*)&qll[qbase + quad*8];
  s16x8 qv1 = *(const s16x8*)&qll[qbase + 32 + quad*8];
  f32x4 s[16];
  #pragma unroll
  for (int kt=0;kt<16;kt++){
    size_t kb = ((size_t)bh*M_ + kt*16 + l16)*D_;
    s16x8 kh0 = *(const s16x8*)&klh[kb + quad*8];
    s16x8 kh1 = *(const s16x8*)&klh[kb + 32 + quad*8];
    s16x8 kv0 = *(const s16x8*)&kll[kb + quad*8];
    s16x8 kv1 = *(const s16x8*)&kll[kb + 32 + quad*8];
    f32x4 z = (f32x4){0.f,0.f,0.f,0.f};
    z = __builtin_amdgcn_mfma_f32_16x16x32_bf16(qh0, kh0, z, 0,0,0);
    z = __builtin_amdgcn_mfma_f32_16x16x32_bf16(qh1, kh1, z, 0,0,0);
    z = __builtin_amdgcn_mfma_f32_16x16x32_bf16(qh0, kv0, z, 0,0,0);
    z = __builtin_amdgcn_mfma_f32_16x16x32_bf16(qh1, kv1, z, 0,0,0);
    z = __builtin_amdgcn_mfma_f32_16x16x32_bf16(qv0, kh0, z, 0,0,0);
    z = __builtin_amdgcn_mfma_f32_16x16x32_bf16(qv1, kh1, z, 0,0,0);
    s[kt] = z;
  }
  float mx[4], inv[4];
  #pragma unroll
  for (int r=0;r<4;r++){
    float m = s[0][r];
    #pragma unroll
    for (int kt=1;kt<16;kt++) m = fmaxf(m, s[kt][r]);
    m = fmaxf(m, __shfl_xor(m, 1));
    m = fmaxf(m, __shfl_xor(m, 2));
    m = fmaxf(m, __shfl_xor(m, 4));
    m = fmaxf(m, __shfl_xor(m, 8));
    mx[r] = m;
  }
  float lsum[4] = {0.f,0.f,0.f,0.f};
  #pragma unroll
  for (int kt=0;kt<16;kt++){
    #pragma unroll
    for (int r=0;r<4;r++){
      float e = expf(s[kt][r] - mx[r]);
      s[kt][r] = e;
      lsum[r] += e;
    }
  }
  #pragma unroll
  for (int r=0;r<4;r++){
    float ls = lsum[r];
    ls += __shfl_xor(ls, 1);
    ls += __shfl_xor(ls, 2);
    ls += __shfl_xor(ls, 4);
    ls += __shfl_xor(ls, 8);
    inv[r] = 1.f/ls;
  }
  if (l16 == 0){
    #pragma unroll
    for (int r=0;r<4;r++) rs[(size_t)bh*M_ + rowtile + quad*4 + r] = 1.0f;
  }
  #pragma unroll
  for (int kt=0;kt<16;kt++){
    int c = kt*16 + l16;
    float csum = 0.f;
    #pragma unroll
    for (int r=0;r<4;r++){
      float p = s[kt][r]*inv[r];
      csum += p;
      size_t oi = mo + (size_t)(rowtile + quad*4 + r)*M_ + c;
      a2f[oi] = p;
      ushort_t hh = f2bf(p);
      a2h[oi] = hh;
      a2l[oi] = f2bf(p - bf2f(hh));
    }
    csum += __shfl_xor(csum, 16);
    csum += __shfl_xor(csum, 32);
    if (lane < 16) atomicAdd(&cs[(size_t)bh*M_ + c], csum);
  }
}

__global__ __launch_bounds__(256) void maxred_k(const float* __restrict__ cs,
    const float* __restrict__ rs, float* __restrict__ scal){
  __shared__ float sm[4];
  float cm=-1e30f, rm=-1e30f;
  for (int i=threadIdx.x;i<BH*M_;i+=256){ cm=fmaxf(cm,cs[i]); rm=fmaxf(rm,rs[i]); }
  cm = blk_max256(cm, sm);
  rm = blk_max256(rm, sm);
  if (threadIdx.x==0) scal[0] = 1.f/(cm*rm);
}

// ---------- initz: z0 = scal*a2^T -> natural splits + T splits ----------
__global__ __launch_bounds__(256) void initz3_k(const float* __restrict__ a2,
    const float* __restrict__ scal,
    ushort_t* __restrict__ zh, ushort_t* __restrict__ zl,
    ushort_t* __restrict__ zTh, ushort_t* __restrict__ zTl){
  __shared__ float tile[64][65];
  int bh = blockIdx.z;
  size_t mo = (size_t)bh*M_*M_;
  float s = scal[0];
  int r0 = blockIdx.y*64, c0 = blockIdx.x*64;
  int t = threadIdx.x, c = t & 63, r4 = t >> 6;
  #pragma unroll
  for (int i=0;i<16;i++){
    int rr = r4 + i*4;
    float v = a2[mo + (size_t)(r0+rr)*M_ + c0 + c] * s;
    tile[rr][c] = v;
    ushort_t hh = f2bf(v);
    size_t oi = mo + (size_t)(r0+rr)*M_ + c0 + c;
    zTh[oi] = hh;
    zTl[oi] = f2bf(v - bf2f(hh));
  }
  __syncthreads();
  #pragma unroll
  for (int i=0;i<16;i++){
    int zr = r4 + i*4;
    float v = tile[c][zr];
    size_t oi = mo + (size_t)(c0+zr)*M_ + r0 + c;
    ushort_t hh = f2bf(v);
    zh[oi] = hh;
    zl[oi] = f2bf(v - bf2f(hh));
  }
}

// ---------- Newton-Schulz split-bf16 MFMA GEMM v2: 128x64 tiles, 512 thr ----------
// C = scale*(coef*A - A@B). A natural splits; B as transposed splits.
// coef matrix IS A (true for all NS steps). Writes natural and/or T splits (+f32).
template<bool HASCOEF, bool WN, bool WT, bool WF>
__global__ __launch_bounds__(512) void ns2_k(
    const ushort_t* __restrict__ Ah, const ushort_t* __restrict__ Al,
    const ushort_t* __restrict__ BTh, const ushort_t* __restrict__ BTl,
    float coef, float scale,
    ushort_t* __restrict__ Ch, ushort_t* __restrict__ Cl,
    ushort_t* __restrict__ CTh, ushort_t* __restrict__ CTl,
    float* __restrict__ Cf){
  __shared__ __align__(16) ushort_t Ahs[128*72];
  __shared__ __align__(16) ushort_t Als[128*72];
  __shared__ __align__(16) ushort_t Bhs[64*72];
  __shared__ __align__(16) ushort_t Bls[64*72];
  int batch = blockIdx.z;
  size_t mo = (size_t)batch*M_*M_;
  int row0 = blockIdx.y*128, col0 = blockIdx.x*64;
  int t = threadIdx.x, lane = t & 63, wave = t >> 6;
  int l16 = lane & 15, quad = lane >> 4;
  f32x4 acc[4];
  #pragma unroll
  for (int j=0;j<4;j++) acc[j] = (f32x4){0.f,0.f,0.f,0.f};
  int sr = t >> 3, sc = (t & 7) * 8;
  for (int k0=0;k0<M_;k0+=64){
    __syncthreads();
    #pragma unroll
    for (int p=0;p<2;p++){
      int r = sr + p*64;
      *(uint4*)&Ahs[r*72 + sc] = *(const uint4*)&Ah[mo + (size_t)(row0+r)*M_ + k0 + sc];
      *(uint4*)&Als[r*72 + sc] = *(const uint4*)&Al[mo + (size_t)(row0+r)*M_ + k0 + sc];
    }
    *(uint4*)&Bhs[sr*72 + sc] = *(const uint4*)&BTh[mo + (size_t)(col0+sr)*M_ + k0 + sc];
    *(uint4*)&Bls[sr*72 + sc] = *(const uint4*)&BTl[mo + (size_t)(col0+sr)*M_ + k0 + sc];
    __syncthreads();
    s16x8 fah[2], fal[2];
    #pragma unroll
    for (int kk=0;kk<2;kk++){
      fah[kk] = *(const s16x8*)&Ahs[(wave*16 + l16)*72 + kk*32 + quad*8];
      fal[kk] = *(const s16x8*)&Als[(wave*16 + l16)*72 + kk*32 + quad*8];
    }
    #pragma unroll
    for (int nt=0;nt<4;nt++){
      #pragma unroll
      for (int kk=0;kk<2;kk++){
        s16x8 fbh = *(const s16x8*)&Bhs[(nt*16 + l16)*72 + kk*32 + quad*8];
        s16x8 fbl = *(const s16x8*)&Bls[(nt*16 + l16)*72 + kk*32 + quad*8];
        acc[nt] = __builtin_amdgcn_mfma_f32_16x16x32_bf16(fah[kk], fbh, acc[nt], 0,0,0);
        acc[nt] = __builtin_amdgcn_mfma_f32_16x16x32_bf16(fah[kk], fbl, acc[nt], 0,0,0);
        acc[nt] = __builtin_amdgcn_mfma_f32_16x16x32_bf16(fal[kk], fbh, acc[nt], 0,0,0);
      }
    }
  }
  int rbase = row0 + wave*16 + quad*4;
  #pragma unroll
  for (int nt=0;nt<4;nt++){
    int c = col0 + nt*16 + l16;
    ushort_t th[4], tl[4];
    #pragma unroll
    for (int reg=0;reg<4;reg++){
      float a = acc[nt][reg];
      float base = 0.f;
      if (HASCOEF){
        size_t ai = mo + (size_t)(rbase+reg)*M_ + c;
        base = coef*(bf2f(Ah[ai]) + bf2f(Al[ai]));
      }
      float v = scale*(base - a);
      if (WF) Cf[mo + (size_t)(rbase+reg)*M_ + c] = v;
      ushort_t hh = f2bf(v);
      ushort_t ll = f2bf(v - bf2f(hh));
      if (WN){
        Ch[mo + (size_t)(rbase+reg)*M_ + c] = hh;
        Cl[mo + (size_t)(rbase+reg)*M_ + c] = ll;
      }
      th[reg] = hh; tl[reg] = ll;
    }
    if (WT){
      uint2 vh; vh.x = (unsigned)th[0] | ((unsigned)th[1]<<16); vh.y = (unsigned)th[2] | ((unsigned)th[3]<<16);
      uint2 vl; vl.x = (unsigned)tl[0] | ((unsigned)tl[1]<<16); vl.y = (unsigned)tl[2] | ((unsigned)tl[3]<<16);
      *(uint2*)&CTh[mo + (size_t)c*M_ + rbase] = vh;
      *(uint2*)&CTl[mo + (size_t)c*M_ + rbase] = vl;
    }
  }
}

// ---------- per-wave-full-row flash attention: 64 q-rows/block ----------
template<int ITERS, bool SCATTER>
__global__ __launch_bounds__(256) void attn5_k(const ushort_t* __restrict__ Q,
    const ushort_t* __restrict__ K, const ushort_t* __restrict__ VT,
    int nq, int nk,
    float* __restrict__ up, float* __restrict__ mst, float* __restrict__ lst,
    ushort_t* __restrict__ ob){
  __shared__ __align__(16) ushort_t Ks[128*72];
  __shared__ __align__(16) ushort_t Vs[64*136];
  __shared__ __align__(16) ushort_t Pb[4*16*136];
  int bh = blockIdx.z, qblk = blockIdx.x, half = blockIdx.y;
  int key0 = half * (ITERS*128);
  int t = threadIdx.x, wave = t >> 6, lane = t & 63;
  int l16 = lane & 15, quad = lane >> 4;
  size_t qbase = ((size_t)bh*nq + qblk*64 + wave*16 + l16)*D_;
  s16x8 qa0 = *(const s16x8*)&Q[qbase + quad*8];
  s16x8 qa1 = *(const s16x8*)&Q[qbase + 32 + quad*8];
  const ushort_t* Kb = K + (size_t)bh*nk*D_;
  const ushort_t* Vb = VT + (size_t)bh*D_*nk;
  ushort_t* Pw = &Pb[wave*16*136];
  float m_r[4], l_r[4];
  #pragma unroll
  for (int r=0;r<4;r++){ m_r[r] = -1e30f; l_r[r] = 0.f; }
  f32x4 oacc[4];
  #pragma unroll
  for (int d=0;d<4;d++) oacc[d] = (f32x4){0.f,0.f,0.f,0.f};
  for (int it=0; it<ITERS; it++){
    int j0 = key0 + it*128;
    __syncthreads();
    #pragma unroll
    for (int p=0;p<4;p++){
      int idx = t + p*256;
      int kr = idx >> 3, kc = (idx & 7)*8;
      *(uint4*)&Ks[kr*72 + kc] = *(const uint4*)&Kb[(size_t)(j0+kr)*D_ + kc];
      int vd = idx >> 4, vc = (idx & 15)*8;
      *(uint4*)&Vs[vd*136 + vc] = *(const uint4*)&Vb[(size_t)vd*nk + j0 + vc];
    }
    __syncthreads();
    f32x4 s[8];
    #pragma unroll
    for (int kt=0;kt<8;kt++){
      s16x8 b0 = *(const s16x8*)&Ks[(kt*16 + l16)*72 + quad*8];
      s16x8 b1 = *(const s16x8*)&Ks[(kt*16 + l16)*72 + 32 + quad*8];
      f32x4 z = (f32x4){0.f,0.f,0.f,0.f};
      z = __builtin_amdgcn_mfma_f32_16x16x32_bf16(qa0, b0, z, 0,0,0);
      z = __builtin_amdgcn_mfma_f32_16x16x32_bf16(qa1, b1, z, 0,0,0);
      s[kt] = z;
    }
    float alpha[4], lsum[4];
    #pragma unroll
    for (int r=0;r<4;r++){
      float mx = s[0][r];
      #pragma unroll
      for (int kt=1;kt<8;kt++) mx = fmaxf(mx, s[kt][r]);
      mx = fmaxf(mx, __shfl_xor(mx, 1));
      mx = fmaxf(mx, __shfl_xor(mx, 2));
      mx = fmaxf(mx, __shfl_xor(mx, 4));
      mx = fmaxf(mx, __shfl_xor(mx, 8));
      float mn = fmaxf(m_r[r], mx);
      alpha[r] = __expf(m_r[r] - mn);
      m_r[r] = mn;
      lsum[r] = 0.f;
    }
    #pragma unroll
    for (int kt=0;kt<8;kt++){
      #pragma unroll
      for (int r=0;r<4;r++){
        float p = __expf(s[kt][r] - m_r[r]);
        Pw[(quad*4+r)*136 + kt*16 + l16] = f2bf(p);
        lsum[r] += p;
      }
    }
    #pragma unroll
    for (int r=0;r<4;r++){
      float ls = lsum[r];
      ls += __shfl_xor(ls, 1);
      ls += __shfl_xor(ls, 2);
      ls += __shfl_xor(ls, 4);
      ls += __shfl_xor(ls, 8);
      l_r[r] = l_r[r]*alpha[r] + ls;
      #pragma unroll
      for (int d=0;d<4;d++) oacc[d][r] *= alpha[r];
    }
    #pragma unroll
    for (int ks=0;ks<4;ks++){
      s16x8 pa = *(const s16x8*)&Pw[l16*136 + ks*32 + quad*8];
      #pragma unroll
      for (int dt=0;dt<4;dt++){
        s16x8 vv = *(const s16x8*)&Vs[(dt*16 + l16)*136 + ks*32 + quad*8];
        oacc[dt] = __builtin_amdgcn_mfma_f32_16x16x32_bf16(pa, vv, oacc[dt], 0,0,0);
      }
    }
  }
  int rowbase = qblk*64 + wave*16 + quad*4;
  if (SCATTER){
    int b = bh >> 3, h = bh & 7;
    #pragma unroll
    for (int dt=0;dt<4;dt++){
      #pragma unroll
      for (int r=0;r<4;r++){
        int n = rowbase + r;
        ob[((size_t)(b*N_ + n))*DIM_ + h*D_ + dt*16 + l16] = f2bf(oacc[dt][r] / l_r[r]);
      }
    }
  } else {
    size_t pb = ((size_t)(half*BH + bh)*M_ + rowbase)*D_;
    #pragma unroll
    for (int dt=0;dt<4;dt++){
      #pragma unroll
      for (int r=0;r<4;r++)
        up[pb + (size_t)r*D_ + dt*16 + l16] = oacc[dt][r];
    }
    if (l16 == 0){
      #pragma unroll
      for (int r=0;r<4;r++){
        size_t si = (size_t)(half*BH + bh)*M_ + rowbase + r;
        mst[si] = m_r[r];
        lst[si] = l_r[r];
      }
    }
  }
}

// ---------- combine 4 key-split partials -> u fp32 ----------
__global__ __launch_bounds__(256) void comb_k(const float* __restrict__ up,
    const float* __restrict__ mst, const float* __restrict__ lst,
    float* __restrict__ u){
  int idx = blockIdx.x*256 + threadIdx.x;
  int d = idx & 63; int row = (idx >> 6) & 255; int bh = idx >> 14;
  float m = -1e30f;
  float mv[4];
  #pragma unroll
  for (int hfs=0;hfs<4;hfs++){
    mv[hfs] = mst[(size_t)(hfs*BH + bh)*M_ + row];
    m = fmaxf(m, mv[hfs]);
  }
  float num = 0.f, den = 0.f;
  #pragma unroll
  for (int hfs=0;hfs<4;hfs++){
    float w = __expf(mv[hfs] - m);
    size_t ri = (size_t)(hfs*BH + bh)*M_ + row;
    den += lst[ri] * w;
    num += up[ri*D_ + d] * w;
  }
  u[idx] = num / den;
}

// ---------- w = z @ u (fp32) ----------
__global__ void zu_k(const float* __restrict__ z, const float* __restrict__ u,
                     float* __restrict__ w){
  int idx = blockIdx.x*256 + threadIdx.x;
  int d = idx & 63, i = (idx >> 6) & 255, bh = idx >> 14;
  const float* zr = z + ((size_t)bh*M_+i)*M_;
  const float* ub = u + (size_t)bh*M_*D_ + d;
  float acc = 0.f;
  for (int kk=0;kk<M_;kk++) acc += zr[kk]*ub[(size_t)kk*D_];
  w[idx] = acc;
}

// ---------- depthwise conv residual, register-tiled ----------
__global__ __launch_bounds__(256) void conv2_k(const ushort_t* __restrict__ v,
    const float* __restrict__ cw, ushort_t* __restrict__ ob){
  int bh = blockIdx.y;
  int h = bh & 7, b = bh >> 3;
  int t = threadIdx.x;
  int d8 = (t & 7) * 8;
  int nloc = t >> 3;
  int n0 = blockIdx.x * 256 + nloc * 8;
  __shared__ float wsm[33];
  if (t < 33) wsm[t] = cw[h*33 + t];
  __syncthreads();
  float wr[33];
  #pragma unroll
  for (int i=0;i<33;i++) wr[i] = wsm[i];
  float acc[8][8];
  #pragma unroll
  for (int j=0;j<8;j++)
    #pragma unroll
    for (int dd=0;dd<8;dd++) acc[j][dd] = 0.f;
  const ushort_t* vbase = v + (size_t)bh*N_*D_;
  #pragma unroll
  for (int r=0;r<40;r++){
    int nn = n0 - 16 + r;
    float vals[8];
    if (nn >= 0 && nn < N_){
      uint4 raw = *(const uint4*)&vbase[(size_t)nn*D_ + d8];
      const ushort_t* pr = (const ushort_t*)&raw;
      #pragma unroll
      for (int dd=0;dd<8;dd++) vals[dd] = bf2f(pr[dd]);
    } else {
      #pragma unroll
      for (int dd=0;dd<8;dd++) vals[dd] = 0.f;
    }
    #pragma unroll
    for (int j=0;j<8;j++){
      int tap = r - j;
      if (tap >= 0 && tap <= 32){
        float wj = wr[tap];
        #pragma unroll
        for (int dd=0;dd<8;dd++) acc[j][dd] += wj * vals[dd];
      }
    }
  }
  #pragma unroll
  for (int j=0;j<8;j++){
    size_t oi = ((size_t)(b*N_ + n0 + j))*DIM_ + h*D_ + d8;
    uint4 cur = *(uint4*)&ob[oi];
    ushort_t* pc = (ushort_t*)&cur;
    #pragma unroll
    for (int dd=0;dd<8;dd++) pc[dd] = f2bf(bf2f(pc[dd]) + acc[j][dd]);
    *(uint4*)&ob[oi] = cur;
  }
}

extern "C" void kernel_launch(void* const* d_in, const int* in_sizes, int n_in,
                              void* d_out, int out_size, void* d_ws, size_t ws_size,
                              hipStream_t stream){
  (void)in_sizes; (void)n_in; (void)out_size; (void)ws_size;
  const float* x      = (const float*)d_in[0];
  const float* gamma  = (const float*)d_in[1];
  const float* beta   = (const float*)d_in[2];
  const float* w_qkv  = (const float*)d_in[3];
  const float* w_out  = (const float*)d_in[4];
  const float* b_out  = (const float*)d_in[5];
  const float* conv_w = (const float*)d_in[6];
  float* y = (float*)d_out;
  float* ws = (float*)d_ws;

  size_t off = 0;
  ushort_t* xnb   = (ushort_t*)(ws + off); off += 4194304;   // reused as az splits
  ushort_t* qb    = (ushort_t*)(ws + off); off += 4194304;
  ushort_t* kb    = (ushort_t*)(ws + off); off += 4194304;
  ushort_t* vb    = (ushort_t*)(ws + off); off += 4194304;
  ushort_t* vT    = (ushort_t*)(ws + off); off += 4194304;
  ushort_t* wqkvT = (ushort_t*)(ws + off); off += 393216;
  ushort_t* woutT = (ushort_t*)(ws + off); off += 131072;
  ushort_t* qlh   = (ushort_t*)(ws + off); off += 262144;
  ushort_t* qll   = (ushort_t*)(ws + off); off += 262144;
  ushort_t* klh   = (ushort_t*)(ws + off); off += 262144;
  ushort_t* kll   = (ushort_t*)(ws + off); off += 262144;
  ushort_t* wzT   = (ushort_t*)(ws + off); off += 262144;
  ushort_t* ob    = (ushort_t*)(ws + off); off += 4194304;
  ushort_t* a2h   = (ushort_t*)(ws + off); off += 1048576;
  ushort_t* a2l   = (ushort_t*)(ws + off); off += 1048576;
  ushort_t* z0h   = (ushort_t*)(ws + off); off += 1048576;
  ushort_t* z0l   = (ushort_t*)(ws + off); off += 1048576;
  ushort_t* z0Th  = (ushort_t*)(ws + off); off += 1048576;
  ushort_t* z0Tl  = (ushort_t*)(ws + off); off += 1048576;
  ushort_t* z1h   = (ushort_t*)(ws + off); off += 1048576;
  ushort_t* z1l   = (ushort_t*)(ws + off); off += 1048576;
  ushort_t* z1Th  = (ushort_t*)(ws + off); off += 1048576;
  ushort_t* z1Tl  = (ushort_t*)(ws + off); off += 1048576;
  ushort_t* t1Th  = (ushort_t*)(ws + off); off += 1048576;
  ushort_t* t1Tl  = (ushort_t*)(ws + off); off += 1048576;
  ushort_t* t2Th  = (ushort_t*)(ws + off); off += 1048576;
  ushort_t* t2Tl  = (ushort_t*)(ws + off); off += 1048576;
  float* ql  = ws + off;  off += 524288;
  float* kl  = ws + off;  off += 524288;
  float* a2f = ws + off;  off += 2097152;
  float* zf  = ws + off;  off += 2097152;
  float* u   = ws + off;  off += 524288;
  float* wz  = ws + off;  off += 524288;
  float* up  = ws + off;  off += 2097152;
  float* mstat = ws + off; off += 32768;
  float* lstat = ws + off; off += 32768;
  float* cs  = ws + off;  off += 8192;
  float* rs  = ws + off;  off += 8192;
  float* scal = ws + off; off += 8;
  ushort_t* azh  = xnb;
  ushort_t* azl  = xnb + 2097152;
  ushort_t* azTh = xnb + 2*2097152;
  ushort_t* azTl = xnb + 3*2097152;

  hipMemsetAsync(cs, 0, BH*M_*sizeof(float), stream);
  ln_k<<<16384,256,0,stream>>>(x, gamma, beta, xnb);
  twb_k<<<dim3(24,8,1),256,0,stream>>>(w_qkv, wqkvT, 512, 1536);
  twb_k<<<dim3(8,8,1),256,0,stream>>>(w_out, woutT, 512, 512);
  gemm_qkv_k<<<dim3(12,128),256,0,stream>>>(xnb, wqkvT, qb, kb, vb);
  tbb_k<<<dim3(1,64,32),256,0,stream>>>(vb, vT, 4096, 64);
  lmk_k<<<2048,256,0,stream>>>(qb, kb, ql, kl, qlh, qll, klh, kll);
  attn2m_k<<<dim3(4,32),256,0,stream>>>(qlh, qll, klh, kll, a2f, a2h, a2l, cs, rs);
  maxred_k<<<1,256,0,stream>>>(cs, rs, scal);
  initz3_k<<<dim3(4,4,32),256,0,stream>>>(a2f, scal, z0h, z0l, z0Th, z0Tl);

  ushort_t *zch = z0h, *zcl = z0l, *zcTh = z0Th, *zcTl = z0Tl;
  ushort_t *znh = z1h, *znl = z1l, *znTh = z1Th, *znTl = z1Tl;
  dim3 nsg(4,2,32);
  for (int it=0; it<6; it++){
    // az = a2@z
    ns2_k<false,true,true,false><<<nsg,512,0,stream>>>(a2h, a2l, zcTh, zcTl,
        0.f, -1.f, azh, azl, azTh, azTl, (float*)nullptr);
    // t1 = 7az - az@az
    ns2_k<true,false,true,false><<<nsg,512,0,stream>>>(azh, azl, azTh, azTl,
        7.f, 1.f, (ushort_t*)nullptr, (ushort_t*)nullptr, t1Th, t1Tl, (float*)nullptr);
    // t2 = 15az - az@t1
    ns2_k<true,false,true,false><<<nsg,512,0,stream>>>(azh, azl, t1Th, t1Tl,
        15.f, 1.f, (ushort_t*)nullptr, (ushort_t*)nullptr, t2Th, t2Tl, (float*)nullptr);
    // z' = 0.25*(13z - z@t2)
    if (it < 5)
      ns2_k<true,true,true,false><<<nsg,512,0,stream>>>(zch, zcl, t2Th, t2Tl,
          13.f, 0.25f, znh, znl, znTh, znTl, (float*)nullptr);
    else
      ns2_k<true,true,true,true><<<nsg,512,0,stream>>>(zch, zcl, t2Th, t2Tl,
          13.f, 0.25f, znh, znl, znTh, znTl, zf);
    { ushort_t* tp;
      tp=zch; zch=znh; znh=tp;  tp=zcl; zcl=znl; znl=tp;
      tp=zcTh; zcTh=znTh; znTh=tp;  tp=zcTl; zcTl=znTl; znTl=tp; }
  }

  attn5_k<8,false><<<dim3(4,4,32),256,0,stream>>>(qlh, kb, vT, M_, N_,
      up, mstat, lstat, (ushort_t*)nullptr);
  comb_k<<<2048,256,0,stream>>>(up, mstat, lstat, u);
  zu_k<<<2048,256,0,stream>>>(zf, u, wz);
  twb_k<<<dim3(1,4,32),256,0,stream>>>(wz, wzT, 256, 64);
  attn5_k<2,true><<<dim3(64,1,32),256,0,stream>>>(qb, klh, wzT, N_, M_,
      (float*)nullptr, (float*)nullptr, (float*)nullptr, ob);
  conv2_k<<<dim3(16,32),256,0,stream>>>(vb, conv_w, ob);
  final_k<<<dim3(4,128),256,0,stream>>>(ob, woutT, b_out, x, y);
}

// Round 7
// 687.305 us; speedup vs baseline: 1.2410x; 1.2410x over previous
//
#include <hip/hip_runtime.h>
#include <math.h>

#define BH 32
#define N_ 4096
#define D_ 64
#define M_ 256
#define L_ 16
#define DIM_ 512
#define K3_ 1536

typedef __attribute__((ext_vector_type(4))) float f32x4;
typedef __attribute__((ext_vector_type(8))) short s16x8;
typedef unsigned short ushort_t;

__device__ inline ushort_t f2bf(float f){
  union{float f; unsigned u;} v; v.f = f;
  unsigned r = v.u + 0x7fffu + ((v.u >> 16) & 1u);
  return (ushort_t)(r >> 16);
}
__device__ inline float bf2f(ushort_t b){
  union{unsigned u; float f;} v; v.u = ((unsigned)b) << 16; return v.f;
}

// ---------- reduction helpers ----------
__device__ inline float wave_sum(float v){
  #pragma unroll
  for (int o=32;o;o>>=1) v += __shfl_down(v,o,64);
  return v;
}
__device__ inline float wave_max(float v){
  #pragma unroll
  for (int o=32;o;o>>=1) v = fmaxf(v,__shfl_down(v,o,64));
  return v;
}
__device__ inline float blk_sum256(float v, float* sm){
  v = wave_sum(v);
  int lane = threadIdx.x & 63, wid = threadIdx.x >> 6;
  if (lane==0) sm[wid]=v;
  __syncthreads();
  float r = sm[0]+sm[1]+sm[2]+sm[3];
  __syncthreads();
  return r;
}
__device__ inline float blk_max256(float v, float* sm){
  v = wave_max(v);
  int lane = threadIdx.x & 63, wid = threadIdx.x >> 6;
  if (lane==0) sm[wid]=v;
  __syncthreads();
  float r = fmaxf(fmaxf(sm[0],sm[1]),fmaxf(sm[2],sm[3]));
  __syncthreads();
  return r;
}

// ---------- 1. LayerNorm -> bf16 ----------
__global__ __launch_bounds__(256) void ln_k(const float* __restrict__ x,
    const float* __restrict__ g, const float* __restrict__ bt, ushort_t* __restrict__ xn){
  int row = blockIdx.x, t = threadIdx.x;
  __shared__ float sm[4];
  const float* xr = x + (size_t)row*DIM_;
  float v0 = xr[t], v1 = xr[t+256];
  float mu = blk_sum256(v0+v1, sm) * (1.f/DIM_);
  float d0 = v0-mu, d1 = v1-mu;
  float var = blk_sum256(d0*d0+d1*d1, sm) * (1.f/DIM_);
  float rs = rsqrtf(var + 1e-5f);
  ushort_t* xo = xn + (size_t)row*DIM_;
  xo[t]     = f2bf(d0*rs*g[t]     + bt[t]);
  xo[t+256] = f2bf(d1*rs*g[t+256] + bt[t+256]);
}

// ---------- transpose fp32 [R][C] -> bf16 [C][R], batched via z ----------
__global__ __launch_bounds__(256) void twb_k(const float* __restrict__ src,
    ushort_t* __restrict__ dst, int R, int C){
  __shared__ ushort_t tile[64][66];
  size_t boff = (size_t)blockIdx.z * R * C;
  int r0 = blockIdx.y*64, c0 = blockIdx.x*64;
  int t = threadIdx.x, c = t & 63, r4 = t >> 6;
  #pragma unroll
  for (int i=0;i<16;i++){
    int rr = r4 + i*4;
    tile[c][rr] = f2bf(src[boff + (size_t)(r0+rr)*C + (c0+c)]);
  }
  __syncthreads();
  #pragma unroll
  for (int i=0;i<16;i++){
    int cc = r4 + i*4;
    dst[boff + (size_t)(c0+cc)*R + (r0 + c)] = tile[cc][c];
  }
}
// ---------- transpose bf16 [R][C] -> bf16 [C][R], batched ----------
__global__ __launch_bounds__(256) void tbb_k(const ushort_t* __restrict__ src,
    ushort_t* __restrict__ dst, int R, int C){
  __shared__ ushort_t tile[64][66];
  size_t boff = (size_t)blockIdx.z * R * C;
  int r0 = blockIdx.y*64, c0 = blockIdx.x*64;
  int t = threadIdx.x, c = t & 63, r4 = t >> 6;
  #pragma unroll
  for (int i=0;i<16;i++){
    int rr = r4 + i*4;
    tile[c][rr] = src[boff + (size_t)(r0+rr)*C + (c0+c)];
  }
  __syncthreads();
  #pragma unroll
  for (int i=0;i<16;i++){
    int cc = r4 + i*4;
    dst[boff + (size_t)(c0+cc)*R + (r0 + c)] = tile[cc][c];
  }
}

// ---------- 2. QKV GEMM bf16 MFMA ----------
__global__ __launch_bounds__(256) void gemm_qkv_k(const ushort_t* __restrict__ A,
    const ushort_t* __restrict__ Bt, ushort_t* __restrict__ qb, ushort_t* __restrict__ kb,
    ushort_t* __restrict__ vb){
  __shared__ __align__(16) ushort_t As[128*72];
  __shared__ __align__(16) ushort_t Bs[128*72];
  int t = threadIdx.x;
  int lane = t & 63, wave = t >> 6;
  int l16 = lane & 15, quad = lane >> 4;
  int wm = (wave & 1) * 64, wn = (wave >> 1) * 64;
  int row0 = blockIdx.y * 128, col0 = blockIdx.x * 128;
  f32x4 acc[4][4];
  #pragma unroll
  for (int i=0;i<4;i++)
    #pragma unroll
    for (int j=0;j<4;j++) acc[i][j] = (f32x4){0.f,0.f,0.f,0.f};
  int sr = t >> 3, sc = (t & 7) * 8;
  for (int k0=0;k0<DIM_;k0+=64){
    __syncthreads();
    #pragma unroll
    for (int p=0;p<4;p++){
      int r = sr + p*32;
      *(uint4*)&As[r*72 + sc] = *(const uint4*)&A[(size_t)(row0+r)*DIM_ + k0 + sc];
      *(uint4*)&Bs[r*72 + sc] = *(const uint4*)&Bt[(size_t)(col0+r)*DIM_ + k0 + sc];
    }
    __syncthreads();
    s16x8 af[4][2], bf[4][2];
    #pragma unroll
    for (int mt=0;mt<4;mt++)
      #pragma unroll
      for (int kk=0;kk<2;kk++)
        af[mt][kk] = *(const s16x8*)&As[(wm + mt*16 + l16)*72 + kk*32 + quad*8];
    #pragma unroll
    for (int nt=0;nt<4;nt++)
      #pragma unroll
      for (int kk=0;kk<2;kk++)
        bf[nt][kk] = *(const s16x8*)&Bs[(wn + nt*16 + l16)*72 + kk*32 + quad*8];
    #pragma unroll
    for (int mt=0;mt<4;mt++)
      #pragma unroll
      for (int nt=0;nt<4;nt++)
        #pragma unroll
        for (int kk=0;kk<2;kk++)
          acc[mt][nt] = __builtin_amdgcn_mfma_f32_16x16x32_bf16(af[mt][kk], bf[nt][kk], acc[mt][nt], 0,0,0);
  }
  #pragma unroll
  for (int mt=0;mt<4;mt++){
    #pragma unroll
    for (int nt=0;nt<4;nt++){
      #pragma unroll
      for (int reg=0;reg<4;reg++){
        int row = row0 + wm + mt*16 + quad*4 + reg;
        int col = col0 + wn + nt*16 + l16;
        float val = acc[mt][nt][reg];
        int b = row >> 12, n = row & 4095;
        int which = col >> 9, rem = col & 511;
        int h = rem >> 6, d = rem & 63;
        size_t dst = ((size_t)((b<<3)+h)*N_ + n)*D_ + d;
        if (which==0)      qb[dst] = f2bf(val*0.125f);
        else if (which==1) kb[dst] = f2bf(val);
        else               vb[dst] = f2bf(val);
      }
    }
  }
}

// ---------- final GEMM bf16 MFMA ----------
__global__ __launch_bounds__(256) void final_k(const ushort_t* __restrict__ A,
    const ushort_t* __restrict__ Bt, const float* __restrict__ bo,
    const float* __restrict__ x, float* __restrict__ y){
  __shared__ __align__(16) ushort_t As[128*72];
  __shared__ __align__(16) ushort_t Bs[128*72];
  int t = threadIdx.x;
  int lane = t & 63, wave = t >> 6;
  int l16 = lane & 15, quad = lane >> 4;
  int wm = (wave & 1) * 64, wn = (wave >> 1) * 64;
  int row0 = blockIdx.y * 128, col0 = blockIdx.x * 128;
  f32x4 acc[4][4];
  #pragma unroll
  for (int i=0;i<4;i++)
    #pragma unroll
    for (int j=0;j<4;j++) acc[i][j] = (f32x4){0.f,0.f,0.f,0.f};
  int sr = t >> 3, sc = (t & 7) * 8;
  for (int k0=0;k0<DIM_;k0+=64){
    __syncthreads();
    #pragma unroll
    for (int p=0;p<4;p++){
      int r = sr + p*32;
      *(uint4*)&As[r*72 + sc] = *(const uint4*)&A[(size_t)(row0+r)*DIM_ + k0 + sc];
      *(uint4*)&Bs[r*72 + sc] = *(const uint4*)&Bt[(size_t)(col0+r)*DIM_ + k0 + sc];
    }
    __syncthreads();
    s16x8 af[4][2], bf[4][2];
    #pragma unroll
    for (int mt=0;mt<4;mt++)
      #pragma unroll
      for (int kk=0;kk<2;kk++)
        af[mt][kk] = *(const s16x8*)&As[(wm + mt*16 + l16)*72 + kk*32 + quad*8];
    #pragma unroll
    for (int nt=0;nt<4;nt++)
      #pragma unroll
      for (int kk=0;kk<2;kk++)
        bf[nt][kk] = *(const s16x8*)&Bs[(wn + nt*16 + l16)*72 + kk*32 + quad*8];
    #pragma unroll
    for (int mt=0;mt<4;mt++)
      #pragma unroll
      for (int nt=0;nt<4;nt++)
        #pragma unroll
        for (int kk=0;kk<2;kk++)
          acc[mt][nt] = __builtin_amdgcn_mfma_f32_16x16x32_bf16(af[mt][kk], bf[nt][kk], acc[mt][nt], 0,0,0);
  }
  #pragma unroll
  for (int mt=0;mt<4;mt++){
    #pragma unroll
    for (int nt=0;nt<4;nt++){
      #pragma unroll
      for (int reg=0;reg<4;reg++){
        int row = row0 + wm + mt*16 + quad*4 + reg;
        int col = col0 + wn + nt*16 + l16;
        size_t o = (size_t)row*DIM_ + col;
        y[o] = acc[mt][nt][reg] + bo[col] + x[o];
      }
    }
  }
}

// ---------- 3. landmark means (fp32 + bf16 h/l splits) ----------
__global__ void lmk_k(const ushort_t* __restrict__ q, const ushort_t* __restrict__ k,
                      float* __restrict__ ql, float* __restrict__ kl,
                      ushort_t* __restrict__ qlh, ushort_t* __restrict__ qll,
                      ushort_t* __restrict__ klh, ushort_t* __restrict__ kll){
  int idx = blockIdx.x*256 + threadIdx.x;
  int d = idx & 63, i = (idx >> 6) & 255, bh = idx >> 14;
  size_t base = ((size_t)bh*N_ + i*L_)*D_ + d;
  float sq=0.f, sk=0.f;
  #pragma unroll
  for (int tt=0;tt<L_;tt++){ sq += bf2f(q[base + (size_t)tt*D_]); sk += bf2f(k[base + (size_t)tt*D_]); }
  sq *= (1.f/L_); sk *= (1.f/L_);
  ql[idx] = sq; kl[idx] = sk;
  ushort_t qh = f2bf(sq), kh = f2bf(sk);
  qlh[idx] = qh; qll[idx] = f2bf(sq - bf2f(qh));
  klh[idx] = kh; kll[idx] = f2bf(sk - bf2f(kh));
}

// ---------- 4. attn2 via split-bf16 MFMA, fused row/col sums ----------
__global__ __launch_bounds__(256) void attn2m_k(
    const ushort_t* __restrict__ qlh, const ushort_t* __restrict__ qll,
    const ushort_t* __restrict__ klh, const ushort_t* __restrict__ kll,
    float* __restrict__ a2f, ushort_t* __restrict__ a2h, ushort_t* __restrict__ a2l,
    float* __restrict__ cs, float* __restrict__ rs){
  int bh = blockIdx.y;
  int t = threadIdx.x, wave = t >> 6, lane = t & 63;
  int l16 = lane & 15, quad = lane >> 4;
  size_t mo = (size_t)bh*M_*M_;
  int rowtile = blockIdx.x*64 + wave*16;
  size_t qbase = ((size_t)bh*M_ + rowtile + l16)*D_;
  s16x8 qh0 = *(const s16x8*)&qlh[qbase + quad*8];
  s16x8 qh1 = *(const s16x8*)&qlh[qbase + 32 + quad*8];
  s16x8 qv0 = *(const s16x8*)&qll[qbase + quad*8];
  s16x8 qv1 = *(const s16x8*)&qll[qbase + 32 + quad*8];
  f32x4 s[16];
  #pragma unroll
  for (int kt=0;kt<16;kt++){
    size_t kb = ((size_t)bh*M_ + kt*16 + l16)*D_;
    s16x8 kh0 = *(const s16x8*)&klh[kb + quad*8];
    s16x8 kh1 = *(const s16x8*)&klh[kb + 32 + quad*8];
    s16x8 kv0 = *(const s16x8*)&kll[kb + quad*8];
    s16x8 kv1 = *(const s16x8*)&kll[kb + 32 + quad*8];
    f32x4 z = (f32x4){0.f,0.f,0.f,0.f};
    z = __builtin_amdgcn_mfma_f32_16x16x32_bf16(qh0, kh0, z, 0,0,0);
    z = __builtin_amdgcn_mfma_f32_16x16x32_bf16(qh1, kh1, z, 0,0,0);
    z = __builtin_amdgcn_mfma_f32_16x16x32_bf16(qh0, kv0, z, 0,0,0);
    z = __builtin_amdgcn_mfma_f32_16x16x32_bf16(qh1, kv1, z, 0,0,0);
    z = __builtin_amdgcn_mfma_f32_16x16x32_bf16(qv0, kh0, z, 0,0,0);
    z = __builtin_amdgcn_mfma_f32_16x16x32_bf16(qv1, kh1, z, 0,0,0);
    s[kt] = z;
  }
  float mx[4], inv[4];
  #pragma unroll
  for (int r=0;r<4;r++){
    float m = s[0][r];
    #pragma unroll
    for (int kt=1;kt<16;kt++) m = fmaxf(m, s[kt][r]);
    m = fmaxf(m, __shfl_xor(m, 1));
    m = fmaxf(m, __shfl_xor(m, 2));
    m = fmaxf(m, __shfl_xor(m, 4));
    m = fmaxf(m, __shfl_xor(m, 8));
    mx[r] = m;
  }
  float lsum[4] = {0.f,0.f,0.f,0.f};
  #pragma unroll
  for (int kt=0;kt<16;kt++){
    #pragma unroll
    for (int r=0;r<4;r++){
      float e = expf(s[kt][r] - mx[r]);
      s[kt][r] = e;
      lsum[r] += e;
    }
  }
  #pragma unroll
  for (int r=0;r<4;r++){
    float ls = lsum[r];
    ls += __shfl_xor(ls, 1);
    ls += __shfl_xor(ls, 2);
    ls += __shfl_xor(ls, 4);
    ls += __shfl_xor(ls, 8);
    inv[r] = 1.f/ls;
  }
  if (l16 == 0){
    #pragma unroll
    for (int r=0;r<4;r++) rs[(size_t)bh*M_ + rowtile + quad*4 + r] = 1.0f;
  }
  #pragma unroll
  for (int kt=0;kt<16;kt++){
    int c = kt*16 + l16;
    float csum = 0.f;
    #pragma unroll
    for (int r=0;r<4;r++){
      float p = s[kt][r]*inv[r];
      csum += p;
      size_t oi = mo + (size_t)(rowtile + quad*4 + r)*M_ + c;
      a2f[oi] = p;
      ushort_t hh = f2bf(p);
      a2h[oi] = hh;
      a2l[oi] = f2bf(p - bf2f(hh));
    }
    csum += __shfl_xor(csum, 16);
    csum += __shfl_xor(csum, 32);
    if (lane < 16) atomicAdd(&cs[(size_t)bh*M_ + c], csum);
  }
}

__global__ __launch_bounds__(256) void maxred_k(const float* __restrict__ cs,
    const float* __restrict__ rs, float* __restrict__ scal){
  __shared__ float sm[4];
  float cm=-1e30f, rm=-1e30f;
  for (int i=threadIdx.x;i<BH*M_;i+=256){ cm=fmaxf(cm,cs[i]); rm=fmaxf(rm,rs[i]); }
  cm = blk_max256(cm, sm);
  rm = blk_max256(rm, sm);
  if (threadIdx.x==0) scal[0] = 1.f/(cm*rm);
}

// ---------- initz: z0 = scal*a2^T -> natural splits + T splits ----------
__global__ __launch_bounds__(256) void initz3_k(const float* __restrict__ a2,
    const float* __restrict__ scal,
    ushort_t* __restrict__ zh, ushort_t* __restrict__ zl,
    ushort_t* __restrict__ zTh, ushort_t* __restrict__ zTl){
  __shared__ float tile[64][65];
  int bh = blockIdx.z;
  size_t mo = (size_t)bh*M_*M_;
  float s = scal[0];
  int r0 = blockIdx.y*64, c0 = blockIdx.x*64;
  int t = threadIdx.x, c = t & 63, r4 = t >> 6;
  #pragma unroll
  for (int i=0;i<16;i++){
    int rr = r4 + i*4;
    float v = a2[mo + (size_t)(r0+rr)*M_ + c0 + c] * s;
    tile[rr][c] = v;
    ushort_t hh = f2bf(v);
    size_t oi = mo + (size_t)(r0+rr)*M_ + c0 + c;
    zTh[oi] = hh;
    zTl[oi] = f2bf(v - bf2f(hh));
  }
  __syncthreads();
  #pragma unroll
  for (int i=0;i<16;i++){
    int zr = r4 + i*4;
    float v = tile[c][zr];
    size_t oi = mo + (size_t)(c0+zr)*M_ + r0 + c;
    ushort_t hh = f2bf(v);
    zh[oi] = hh;
    zl[oi] = f2bf(v - bf2f(hh));
  }
}

// ---------- Newton-Schulz split-bf16 MFMA GEMM: 64x64 tiles, 256 thr ----------
// C = scale*(coef*A - A@B); coef term from A's bf16 splits.
template<bool HASCOEF, bool WN, bool WT, bool WF>
__global__ __launch_bounds__(256) void ns3_k(
    const ushort_t* __restrict__ Ah, const ushort_t* __restrict__ Al,
    const ushort_t* __restrict__ BTh, const ushort_t* __restrict__ BTl,
    float coef, float scale,
    ushort_t* __restrict__ Ch, ushort_t* __restrict__ Cl,
    ushort_t* __restrict__ CTh, ushort_t* __restrict__ CTl,
    float* __restrict__ Cf){
  __shared__ __align__(16) ushort_t Ahs[64*72];
  __shared__ __align__(16) ushort_t Als[64*72];
  __shared__ __align__(16) ushort_t Bhs[64*72];
  __shared__ __align__(16) ushort_t Bls[64*72];
  int batch = blockIdx.z;
  size_t mo = (size_t)batch*M_*M_;
  int row0 = blockIdx.y*64, col0 = blockIdx.x*64;
  int t = threadIdx.x, lane = t & 63, wave = t >> 6;
  int l16 = lane & 15, quad = lane >> 4;
  f32x4 acc[4];
  #pragma unroll
  for (int j=0;j<4;j++) acc[j] = (f32x4){0.f,0.f,0.f,0.f};
  int sr = t >> 3, sc = (t & 7) * 8;
  for (int k0=0;k0<M_;k0+=64){
    __syncthreads();
    #pragma unroll
    for (int p=0;p<2;p++){
      int r = sr + p*32;
      *(uint4*)&Ahs[r*72 + sc] = *(const uint4*)&Ah[mo + (size_t)(row0+r)*M_ + k0 + sc];
      *(uint4*)&Als[r*72 + sc] = *(const uint4*)&Al[mo + (size_t)(row0+r)*M_ + k0 + sc];
      *(uint4*)&Bhs[r*72 + sc] = *(const uint4*)&BTh[mo + (size_t)(col0+r)*M_ + k0 + sc];
      *(uint4*)&Bls[r*72 + sc] = *(const uint4*)&BTl[mo + (size_t)(col0+r)*M_ + k0 + sc];
    }
    __syncthreads();
    s16x8 fah[2], fal[2];
    #pragma unroll
    for (int kk=0;kk<2;kk++){
      fah[kk] = *(const s16x8*)&Ahs[(wave*16 + l16)*72 + kk*32 + quad*8];
      fal[kk] = *(const s16x8*)&Als[(wave*16 + l16)*72 + kk*32 + quad*8];
    }
    #pragma unroll
    for (int nt=0;nt<4;nt++){
      #pragma unroll
      for (int kk=0;kk<2;kk++){
        s16x8 fbh = *(const s16x8*)&Bhs[(nt*16 + l16)*72 + kk*32 + quad*8];
        s16x8 fbl = *(const s16x8*)&Bls[(nt*16 + l16)*72 + kk*32 + quad*8];
        acc[nt] = __builtin_amdgcn_mfma_f32_16x16x32_bf16(fah[kk], fbh, acc[nt], 0,0,0);
        acc[nt] = __builtin_amdgcn_mfma_f32_16x16x32_bf16(fah[kk], fbl, acc[nt], 0,0,0);
        acc[nt] = __builtin_amdgcn_mfma_f32_16x16x32_bf16(fal[kk], fbh, acc[nt], 0,0,0);
      }
    }
  }
  int rbase = row0 + wave*16 + quad*4;
  #pragma unroll
  for (int nt=0;nt<4;nt++){
    int c = col0 + nt*16 + l16;
    ushort_t th[4], tl[4];
    #pragma unroll
    for (int reg=0;reg<4;reg++){
      float a = acc[nt][reg];
      float base = 0.f;
      if (HASCOEF){
        size_t ai = mo + (size_t)(rbase+reg)*M_ + c;
        base = coef*(bf2f(Ah[ai]) + bf2f(Al[ai]));
      }
      float v = scale*(base - a);
      if (WF) Cf[mo + (size_t)(rbase+reg)*M_ + c] = v;
      ushort_t hh = f2bf(v);
      ushort_t ll = f2bf(v - bf2f(hh));
      if (WN){
        Ch[mo + (size_t)(rbase+reg)*M_ + c] = hh;
        Cl[mo + (size_t)(rbase+reg)*M_ + c] = ll;
      }
      th[reg] = hh; tl[reg] = ll;
    }
    if (WT){
      uint2 vh; vh.x = (unsigned)th[0] | ((unsigned)th[1]<<16); vh.y = (unsigned)th[2] | ((unsigned)th[3]<<16);
      uint2 vl; vl.x = (unsigned)tl[0] | ((unsigned)tl[1]<<16); vl.y = (unsigned)tl[2] | ((unsigned)tl[3]<<16);
      *(uint2*)&CTh[mo + (size_t)c*M_ + rbase] = vh;
      *(uint2*)&CTl[mo + (size_t)c*M_ + rbase] = vl;
    }
  }
}

// ---------- per-wave-full-row flash attention: 64 q-rows/block ----------
template<int ITERS, bool SCATTER>
__global__ __launch_bounds__(256) void attn5_k(const ushort_t* __restrict__ Q,
    const ushort_t* __restrict__ K, const ushort_t* __restrict__ VT,
    int nq, int nk,
    float* __restrict__ up, float* __restrict__ mst, float* __restrict__ lst,
    ushort_t* __restrict__ ob){
  __shared__ __align__(16) ushort_t Ks[128*72];
  __shared__ __align__(16) ushort_t Vs[64*136];
  __shared__ __align__(16) ushort_t Pb[4*16*136];
  int bh = blockIdx.z, qblk = blockIdx.x, half = blockIdx.y;
  int key0 = half * (ITERS*128);
  int t = threadIdx.x, wave = t >> 6, lane = t & 63;
  int l16 = lane & 15, quad = lane >> 4;
  size_t qbase = ((size_t)bh*nq + qblk*64 + wave*16 + l16)*D_;
  s16x8 qa0 = *(const s16x8*)&Q[qbase + quad*8];
  s16x8 qa1 = *(const s16x8*)&Q[qbase + 32 + quad*8];
  const ushort_t* Kb = K + (size_t)bh*nk*D_;
  const ushort_t* Vb = VT + (size_t)bh*D_*nk;
  ushort_t* Pw = &Pb[wave*16*136];
  float m_r[4], l_r[4];
  #pragma unroll
  for (int r=0;r<4;r++){ m_r[r] = -1e30f; l_r[r] = 0.f; }
  f32x4 oacc[4];
  #pragma unroll
  for (int d=0;d<4;d++) oacc[d] = (f32x4){0.f,0.f,0.f,0.f};
  for (int it=0; it<ITERS; it++){
    int j0 = key0 + it*128;
    __syncthreads();
    #pragma unroll
    for (int p=0;p<4;p++){
      int idx = t + p*256;
      int kr = idx >> 3, kc = (idx & 7)*8;
      *(uint4*)&Ks[kr*72 + kc] = *(const uint4*)&Kb[(size_t)(j0+kr)*D_ + kc];
      int vd = idx >> 4, vc = (idx & 15)*8;
      *(uint4*)&Vs[vd*136 + vc] = *(const uint4*)&Vb[(size_t)vd*nk + j0 + vc];
    }
    __syncthreads();
    f32x4 s[8];
    #pragma unroll
    for (int kt=0;kt<8;kt++){
      s16x8 b0 = *(const s16x8*)&Ks[(kt*16 + l16)*72 + quad*8];
      s16x8 b1 = *(const s16x8*)&Ks[(kt*16 + l16)*72 + 32 + quad*8];
      f32x4 z = (f32x4){0.f,0.f,0.f,0.f};
      z = __builtin_amdgcn_mfma_f32_16x16x32_bf16(qa0, b0, z, 0,0,0);
      z = __builtin_amdgcn_mfma_f32_16x16x32_bf16(qa1, b1, z, 0,0,0);
      s[kt] = z;
    }
    float alpha[4], lsum[4];
    #pragma unroll
    for (int r=0;r<4;r++){
      float mx = s[0][r];
      #pragma unroll
      for (int kt=1;kt<8;kt++) mx = fmaxf(mx, s[kt][r]);
      mx = fmaxf(mx, __shfl_xor(mx, 1));
      mx = fmaxf(mx, __shfl_xor(mx, 2));
      mx = fmaxf(mx, __shfl_xor(mx, 4));
      mx = fmaxf(mx, __shfl_xor(mx, 8));
      float mn = fmaxf(m_r[r], mx);
      alpha[r] = __expf(m_r[r] - mn);
      m_r[r] = mn;
      lsum[r] = 0.f;
    }
    #pragma unroll
    for (int kt=0;kt<8;kt++){
      #pragma unroll
      for (int r=0;r<4;r++){
        float p = __expf(s[kt][r] - m_r[r]);
        Pw[(quad*4+r)*136 + kt*16 + l16] = f2bf(p);
        lsum[r] += p;
      }
    }
    #pragma unroll
    for (int r=0;r<4;r++){
      float ls = lsum[r];
      ls += __shfl_xor(ls, 1);
      ls += __shfl_xor(ls, 2);
      ls += __shfl_xor(ls, 4);
      ls += __shfl_xor(ls, 8);
      l_r[r] = l_r[r]*alpha[r] + ls;
      #pragma unroll
      for (int d=0;d<4;d++) oacc[d][r] *= alpha[r];
    }
    #pragma unroll
    for (int ks=0;ks<4;ks++){
      s16x8 pa = *(const s16x8*)&Pw[l16*136 + ks*32 + quad*8];
      #pragma unroll
      for (int dt=0;dt<4;dt++){
        s16x8 vv = *(const s16x8*)&Vs[(dt*16 + l16)*136 + ks*32 + quad*8];
        oacc[dt] = __builtin_amdgcn_mfma_f32_16x16x32_bf16(pa, vv, oacc[dt], 0,0,0);
      }
    }
  }
  int rowbase = qblk*64 + wave*16 + quad*4;
  if (SCATTER){
    int b = bh >> 3, h = bh & 7;
    #pragma unroll
    for (int dt=0;dt<4;dt++){
      #pragma unroll
      for (int r=0;r<4;r++){
        int n = rowbase + r;
        ob[((size_t)(b*N_ + n))*DIM_ + h*D_ + dt*16 + l16] = f2bf(oacc[dt][r] / l_r[r]);
      }
    }
  } else {
    size_t pb = ((size_t)(half*BH + bh)*M_ + rowbase)*D_;
    #pragma unroll
    for (int dt=0;dt<4;dt++){
      #pragma unroll
      for (int r=0;r<4;r++)
        up[pb + (size_t)r*D_ + dt*16 + l16] = oacc[dt][r];
    }
    if (l16 == 0){
      #pragma unroll
      for (int r=0;r<4;r++){
        size_t si = (size_t)(half*BH + bh)*M_ + rowbase + r;
        mst[si] = m_r[r];
        lst[si] = l_r[r];
      }
    }
  }
}

// ---------- combine 4 key-split partials -> u fp32 ----------
__global__ __launch_bounds__(256) void comb_k(const float* __restrict__ up,
    const float* __restrict__ mst, const float* __restrict__ lst,
    float* __restrict__ u){
  int idx = blockIdx.x*256 + threadIdx.x;
  int d = idx & 63; int row = (idx >> 6) & 255; int bh = idx >> 14;
  float m = -1e30f;
  float mv[4];
  #pragma unroll
  for (int hfs=0;hfs<4;hfs++){
    mv[hfs] = mst[(size_t)(hfs*BH + bh)*M_ + row];
    m = fmaxf(m, mv[hfs]);
  }
  float num = 0.f, den = 0.f;
  #pragma unroll
  for (int hfs=0;hfs<4;hfs++){
    float w = __expf(mv[hfs] - m);
    size_t ri = (size_t)(hfs*BH + bh)*M_ + row;
    den += lst[ri] * w;
    num += up[ri*D_ + d] * w;
  }
  u[idx] = num / den;
}

// ---------- w = z @ u (fp32) ----------
__global__ void zu_k(const float* __restrict__ z, const float* __restrict__ u,
                     float* __restrict__ w){
  int idx = blockIdx.x*256 + threadIdx.x;
  int d = idx & 63, i = (idx >> 6) & 255, bh = idx >> 14;
  const float* zr = z + ((size_t)bh*M_+i)*M_;
  const float* ub = u + (size_t)bh*M_*D_ + d;
  float acc = 0.f;
  for (int kk=0;kk<M_;kk++) acc += zr[kk]*ub[(size_t)kk*D_];
  w[idx] = acc;
}

// ---------- depthwise conv residual v3: 4n x 8d tile, weights in LDS ----------
__global__ __launch_bounds__(256) void conv3_k(const ushort_t* __restrict__ v,
    const float* __restrict__ cw, ushort_t* __restrict__ ob){
  int bh = blockIdx.y;
  int h = bh & 7, b = bh >> 3;
  int t = threadIdx.x;
  int d8 = (t & 7) * 8;
  int nloc = t >> 3;                       // 0..31
  int n0 = blockIdx.x * 128 + nloc * 4;
  __shared__ float wsm[33];
  if (t < 33) wsm[t] = cw[h*33 + t];
  __syncthreads();
  float acc[4][8];
  #pragma unroll
  for (int j=0;j<4;j++)
    #pragma unroll
    for (int dd=0;dd<8;dd++) acc[j][dd] = 0.f;
  const ushort_t* vbase = v + (size_t)bh*N_*D_;
  for (int r=0;r<36;r++){
    int nn = n0 - 16 + r;
    float vals[8];
    if (nn >= 0 && nn < N_){
      uint4 raw = *(const uint4*)&vbase[(size_t)nn*D_ + d8];
      const ushort_t* pr = (const ushort_t*)&raw;
      #pragma unroll
      for (int dd=0;dd<8;dd++) vals[dd] = bf2f(pr[dd]);
    } else {
      #pragma unroll
      for (int dd=0;dd<8;dd++) vals[dd] = 0.f;
    }
    #pragma unroll
    for (int j=0;j<4;j++){
      int tap = r - j;
      if (tap >= 0 && tap <= 32){
        float wj = wsm[tap];
        #pragma unroll
        for (int dd=0;dd<8;dd++) acc[j][dd] += wj * vals[dd];
      }
    }
  }
  #pragma unroll
  for (int j=0;j<4;j++){
    size_t oi = ((size_t)(b*N_ + n0 + j))*DIM_ + h*D_ + d8;
    uint4 cur = *(uint4*)&ob[oi];
    ushort_t* pc = (ushort_t*)&cur;
    #pragma unroll
    for (int dd=0;dd<8;dd++) pc[dd] = f2bf(bf2f(pc[dd]) + acc[j][dd]);
    *(uint4*)&ob[oi] = cur;
  }
}

extern "C" void kernel_launch(void* const* d_in, const int* in_sizes, int n_in,
                              void* d_out, int out_size, void* d_ws, size_t ws_size,
                              hipStream_t stream){
  (void)in_sizes; (void)n_in; (void)out_size; (void)ws_size;
  const float* x      = (const float*)d_in[0];
  const float* gamma  = (const float*)d_in[1];
  const float* beta   = (const float*)d_in[2];
  const float* w_qkv  = (const float*)d_in[3];
  const float* w_out  = (const float*)d_in[4];
  const float* b_out  = (const float*)d_in[5];
  const float* conv_w = (const float*)d_in[6];
  float* y = (float*)d_out;
  float* ws = (float*)d_ws;

  size_t off = 0;
  ushort_t* xnb   = (ushort_t*)(ws + off); off += 4194304;   // reused as az splits
  ushort_t* qb    = (ushort_t*)(ws + off); off += 4194304;
  ushort_t* kb    = (ushort_t*)(ws + off); off += 4194304;
  ushort_t* vb    = (ushort_t*)(ws + off); off += 4194304;
  ushort_t* vT    = (ushort_t*)(ws + off); off += 4194304;
  ushort_t* wqkvT = (ushort_t*)(ws + off); off += 393216;
  ushort_t* woutT = (ushort_t*)(ws + off); off += 131072;
  ushort_t* qlh   = (ushort_t*)(ws + off); off += 262144;
  ushort_t* qll   = (ushort_t*)(ws + off); off += 262144;
  ushort_t* klh   = (ushort_t*)(ws + off); off += 262144;
  ushort_t* kll   = (ushort_t*)(ws + off); off += 262144;
  ushort_t* wzT   = (ushort_t*)(ws + off); off += 262144;
  ushort_t* ob    = (ushort_t*)(ws + off); off += 4194304;
  ushort_t* a2h   = (ushort_t*)(ws + off); off += 1048576;
  ushort_t* a2l   = (ushort_t*)(ws + off); off += 1048576;
  ushort_t* z0h   = (ushort_t*)(ws + off); off += 1048576;
  ushort_t* z0l   = (ushort_t*)(ws + off); off += 1048576;
  ushort_t* z0Th  = (ushort_t*)(ws + off); off += 1048576;
  ushort_t* z0Tl  = (ushort_t*)(ws + off); off += 1048576;
  ushort_t* z1h   = (ushort_t*)(ws + off); off += 1048576;
  ushort_t* z1l   = (ushort_t*)(ws + off); off += 1048576;
  ushort_t* z1Th  = (ushort_t*)(ws + off); off += 1048576;
  ushort_t* z1Tl  = (ushort_t*)(ws + off); off += 1048576;
  ushort_t* t1Th  = (ushort_t*)(ws + off); off += 1048576;
  ushort_t* t1Tl  = (ushort_t*)(ws + off); off += 1048576;
  ushort_t* t2Th  = (ushort_t*)(ws + off); off += 1048576;
  ushort_t* t2Tl  = (ushort_t*)(ws + off); off += 1048576;
  float* ql  = ws + off;  off += 524288;
  float* kl  = ws + off;  off += 524288;
  float* a2f = ws + off;  off += 2097152;
  float* zf  = ws + off;  off += 2097152;
  float* u   = ws + off;  off += 524288;
  float* wz  = ws + off;  off += 524288;
  float* up  = ws + off;  off += 2097152;
  float* mstat = ws + off; off += 32768;
  float* lstat = ws + off; off += 32768;
  float* cs  = ws + off;  off += 8192;
  float* rs  = ws + off;  off += 8192;
  float* scal = ws + off; off += 8;
  ushort_t* azh  = xnb;
  ushort_t* azl  = xnb + 2097152;
  ushort_t* azTh = xnb + 2*2097152;
  ushort_t* azTl = xnb + 3*2097152;

  hipMemsetAsync(cs, 0, BH*M_*sizeof(float), stream);
  ln_k<<<16384,256,0,stream>>>(x, gamma, beta, xnb);
  twb_k<<<dim3(24,8,1),256,0,stream>>>(w_qkv, wqkvT, 512, 1536);
  twb_k<<<dim3(8,8,1),256,0,stream>>>(w_out, woutT, 512, 512);
  gemm_qkv_k<<<dim3(12,128),256,0,stream>>>(xnb, wqkvT, qb, kb, vb);
  tbb_k<<<dim3(1,64,32),256,0,stream>>>(vb, vT, 4096, 64);
  lmk_k<<<2048,256,0,stream>>>(qb, kb, ql, kl, qlh, qll, klh, kll);
  attn2m_k<<<dim3(4,32),256,0,stream>>>(qlh, qll, klh, kll, a2f, a2h, a2l, cs, rs);
  maxred_k<<<1,256,0,stream>>>(cs, rs, scal);
  initz3_k<<<dim3(4,4,32),256,0,stream>>>(a2f, scal, z0h, z0l, z0Th, z0Tl);

  ushort_t *zch = z0h, *zcl = z0l, *zcTh = z0Th, *zcTl = z0Tl;
  ushort_t *znh = z1h, *znl = z1l, *znTh = z1Th, *znTl = z1Tl;
  dim3 nsg(4,4,32);
  for (int it=0; it<6; it++){
    // az = a2@z
    ns3_k<false,true,true,false><<<nsg,256,0,stream>>>(a2h, a2l, zcTh, zcTl,
        0.f, -1.f, azh, azl, azTh, azTl, (float*)nullptr);
    // t1 = 7az - az@az
    ns3_k<true,false,true,false><<<nsg,256,0,stream>>>(azh, azl, azTh, azTl,
        7.f, 1.f, (ushort_t*)nullptr, (ushort_t*)nullptr, t1Th, t1Tl, (float*)nullptr);
    // t2 = 15az - az@t1
    ns3_k<true,false,true,false><<<nsg,256,0,stream>>>(azh, azl, t1Th, t1Tl,
        15.f, 1.f, (ushort_t*)nullptr, (ushort_t*)nullptr, t2Th, t2Tl, (float*)nullptr);
    // z' = 0.25*(13z - z@t2)
    if (it < 5)
      ns3_k<true,true,true,false><<<nsg,256,0,stream>>>(zch, zcl, t2Th, t2Tl,
          13.f, 0.25f, znh, znl, znTh, znTl, (float*)nullptr);
    else
      ns3_k<true,true,true,true><<<nsg,256,0,stream>>>(zch, zcl, t2Th, t2Tl,
          13.f, 0.25f, znh, znl, znTh, znTl, zf);
    { ushort_t* tp;
      tp=zch; zch=znh; znh=tp;  tp=zcl; zcl=znl; znl=tp;
      tp=zcTh; zcTh=znTh; znTh=tp;  tp=zcTl; zcTl=znTl; znTl=tp; }
  }

  attn5_k<8,false><<<dim3(4,4,32),256,0,stream>>>(qlh, kb, vT, M_, N_,
      up, mstat, lstat, (ushort_t*)nullptr);
  comb_k<<<2048,256,0,stream>>>(up, mstat, lstat, u);
  zu_k<<<2048,256,0,stream>>>(zf, u, wz);
  twb_k<<<dim3(1,4,32),256,0,stream>>>(wz, wzT, 256, 64);
  attn5_k<2,true><<<dim3(64,1,32),256,0,stream>>>(qb, klh, wzT, N_, M_,
      (float*)nullptr, (float*)nullptr, (float*)nullptr, ob);
  conv3_k<<<dim3(32,32),256,0,stream>>>(vb, conv_w, ob);
  final_k<<<dim3(4,128),256,0,stream>>>(ob, woutT, b_out, x, y);
}